// Round 2
// baseline (243.810 us; speedup 1.0000x reference)
//
#include <hip/hip_runtime.h>
#include <math.h>

#define B    128
#define CTRL 1024
#define NN   4096
#define MM   64
#define OD   70     // M + 6
#define NC   8      // n-chunks per batch
#define CHUNK 512   // NN / NC

// DPP-based 16-lane group sum (pure VALU, no LDS pipe).
#define DPP_ADD(v, ctrl)                                                        \
    do {                                                                        \
        int _t = __builtin_amdgcn_update_dpp(0, __float_as_int(v), (ctrl),      \
                                             0xF, 0xF, true);                   \
        (v) += __int_as_float(_t);                                              \
    } while (0)

__device__ inline float sum16(float v) {
    DPP_ADD(v, 0xB1);    // quad_perm xor1
    DPP_ADD(v, 0x4E);    // quad_perm xor2
    DPP_ADD(v, 0x141);   // row_half_mirror
    DPP_ADD(v, 0x140);   // row_mirror
    return v;
}

// ---------------- kernel 1: fused ctrl-GEMV + similarity ---------------------
// grid (NC, B), block 256.
// Each block redundantly computes k (o[0..63]) + o[64] (beta input) for its b:
// 65 dots of length 1024 spread over 4 waves (~1-2 us, hidden under the
// 128 MB HBM sweep). Then ev[n] = exp(beta*cos_sim) for its 512-row chunk,
// staged in LDS and dumped coalesced; zpart[b][c] = chunk sum (no atomics).
__global__ void k_sim(const float* __restrict__ emb,
                      const float* __restrict__ fc_w,
                      const float* __restrict__ fc_b,
                      const float* __restrict__ mem,
                      float* __restrict__ evb,
                      float* __restrict__ zpart) {
    const int c = blockIdx.x;
    const int b = blockIdx.y;
    const int t = threadIdx.x;
    const int n0 = c * CHUNK;
    const size_t boff = (size_t)b * NN;

    __shared__ __align__(16) float k_sh[MM + 1];   // k[0..63], [64]=o_M
    __shared__ __align__(16) float ev_sh[CHUNK];
    __shared__ float kb[2];   // knorm, beta
    __shared__ float red[4];

    // ---- control dots j = 0..64, wave w handles j = w, w+4, ... ----
    {
        const int w = t >> 6, l = t & 63;
        const float4* e4 = (const float4*)(emb + (size_t)b * CTRL);
        float4 e0 = e4[l], e1 = e4[l + 64], e2 = e4[l + 128], e3 = e4[l + 192];
        for (int j = w; j <= MM; j += 4) {
            const float4* w4 = (const float4*)(fc_w + (size_t)j * CTRL);
            float4 w0 = w4[l], w1 = w4[l + 64], w2 = w4[l + 128], w3 = w4[l + 192];
            float s = e0.x * w0.x + e0.y * w0.y + e0.z * w0.z + e0.w * w0.w;
            s += e1.x * w1.x + e1.y * w1.y + e1.z * w1.z + e1.w * w1.w;
            s += e2.x * w2.x + e2.y * w2.y + e2.z * w2.z + e2.w * w2.w;
            s += e3.x * w3.x + e3.y * w3.y + e3.z * w3.z + e3.w * w3.w;
            for (int off = 32; off; off >>= 1) s += __shfl_xor(s, off);
            if (l == 0) k_sh[j] = s + fc_b[j];
        }
    }
    __syncthreads();

    if (t < MM) {                           // wave 0: knorm via shuffle reduce
        float kv = k_sh[t];
        float ss = kv * kv;
        for (int off = 32; off; off >>= 1) ss += __shfl_xor(ss, off);
        if (t == 0) kb[0] = sqrtf(ss);
    } else if (t == MM) {                   // beta = softplus(o[M])
        float x = k_sh[MM];
        kb[1] = fmaxf(x, 0.f) + log1pf(expf(-fabsf(x)));
    }
    __syncthreads();
    const float knorm = kb[0], beta = kb[1];

    const int lane16 = t & 15;
    const int rgrp   = t >> 4;
    const float4 k4 = ((const float4*)k_sh)[lane16];

    float evsum = 0.f;
    #pragma unroll 8
    for (int i = 0; i < 32; ++i) {
        int row = rgrp + i * 16;
        const float4* m4 = (const float4*)(mem + (boff + n0 + row) * MM);
        float4 v = m4[lane16];
        float dot = v.x * k4.x + v.y * k4.y + v.z * k4.z + v.w * k4.w;
        float ssq = v.x * v.x + v.y * v.y + v.z * v.z + v.w * v.w;
        dot = sum16(dot);
        ssq = sum16(ssq);
        if (lane16 == 0) {
            // |beta*sim| <= ~6, exp fp32-safe; softmax shift-invariant
            float e = __expf(beta * dot / (knorm * sqrtf(ssq) + 1e-16f));
            ev_sh[row] = e;
            evsum += e;
        }
    }
    for (int off = 32; off; off >>= 1) evsum += __shfl_xor(evsum, off);
    if ((t & 63) == 0) red[t >> 6] = evsum;
    __syncthreads();
    if (t == 0) zpart[b * NC + c] = red[0] + red[1] + red[2] + red[3];
    // coalesced ev dump (2 KB per block)
    ((float2*)(evb + boff + n0))[t] = ((const float2*)ev_sh)[t];
}

// ---------------- kernel 2: wg/wt/wp + psum partial + rnum partial ----------
// grid (NC, B), block 256. Tail scalars (g, s, gamma) recomputed redundantly
// (5 dots). zsum = fixed-order sum of 8 partials. Second mem sweep is
// Infinity-Cache-resident.
__global__ void k_wr(const float* __restrict__ emb,
                     const float* __restrict__ fc_w,
                     const float* __restrict__ fc_b,
                     const float* __restrict__ mem,
                     const float* __restrict__ w_prev,
                     const float* __restrict__ evb,
                     const float* __restrict__ zpart,
                     float* __restrict__ wpb,
                     float* __restrict__ ppart,
                     float* __restrict__ rpart) {
    const int c = blockIdx.x;
    const int b = blockIdx.y;
    const int t = threadIdx.x;
    const int n0 = c * CHUNK;
    const size_t boff = (size_t)b * NN;

    __shared__ float wg_sh[CHUNK + 2];
    __shared__ float wp_sh[CHUNK];
    __shared__ __align__(16) float4 acc_sh[256];
    __shared__ float osc[5];   // o[65..69]
    __shared__ float red[4];

    // ---- tail control dots j = 65..69 ----
    {
        const int w = t >> 6, l = t & 63;
        const float4* e4 = (const float4*)(emb + (size_t)b * CTRL);
        float4 e0 = e4[l], e1 = e4[l + 64], e2 = e4[l + 128], e3 = e4[l + 192];
        for (int j = MM + 1 + w; j < OD; j += 4) {
            const float4* w4 = (const float4*)(fc_w + (size_t)j * CTRL);
            float4 w0 = w4[l], w1 = w4[l + 64], w2 = w4[l + 128], w3 = w4[l + 192];
            float s = e0.x * w0.x + e0.y * w0.y + e0.z * w0.z + e0.w * w0.w;
            s += e1.x * w1.x + e1.y * w1.y + e1.z * w1.z + e1.w * w1.w;
            s += e2.x * w2.x + e2.y * w2.y + e2.z * w2.z + e2.w * w2.w;
            s += e3.x * w3.x + e3.y * w3.y + e3.z * w3.z + e3.w * w3.w;
            for (int off = 32; off; off >>= 1) s += __shfl_xor(s, off);
            if (l == 0) osc[j - (MM + 1)] = s + fc_b[j];
        }
    }
    // zsum: fixed-order sum of partials (broadcast loads)
    float zsum = 0.f;
    #pragma unroll
    for (int i = 0; i < NC; ++i) zsum += zpart[b * NC + i];
    __syncthreads();

    const float g  = 1.f / (1.f + __expf(-osc[0]));
    const float a0 = osc[1], a1 = osc[2], a2 = osc[3];
    const float mx = fmaxf(a0, fmaxf(a1, a2));
    const float e0s = __expf(a0 - mx), e1s = __expf(a1 - mx), e2s = __expf(a2 - mx);
    const float es = e0s + e1s + e2s;
    const float s0 = e0s / es, s1 = e1s / es, s2 = e2s / es;
    const float xg = osc[4];
    const float gamma = 1.f + fmaxf(xg, 0.f) + log1pf(__expf(-fabsf(xg)));
    const float invsum = 1.f / zsum;

    for (int idx = t; idx < CHUNK + 2; idx += 256) {
        int n = (n0 - 1 + idx) & (NN - 1);
        wg_sh[idx] = g * evb[boff + n] * invsum + (1.f - g) * w_prev[boff + n];
    }
    __syncthreads();

    float wt0 = s0 * wg_sh[t]       + s1 * wg_sh[t + 1]   + s2 * wg_sh[t + 2];
    float wt1 = s0 * wg_sh[t + 256] + s1 * wg_sh[t + 257] + s2 * wg_sh[t + 258];
    float wp0 = __powf(wt0, gamma);
    float wp1 = __powf(wt1, gamma);
    wp_sh[t]       = wp0;
    wp_sh[t + 256] = wp1;
    wpb[boff + n0 + t]       = wp0;
    wpb[boff + n0 + t + 256] = wp1;

    float ps = wp0 + wp1;
    for (int off = 32; off; off >>= 1) ps += __shfl_xor(ps, off);
    if ((t & 63) == 0) red[t >> 6] = ps;
    __syncthreads();
    if (t == 0) ppart[b * NC + c] = red[0] + red[1] + red[2] + red[3];

    // ---- sweep 2: rpart[b,c,:] = sum_n wp[n] * mem[b,n,:] (L3-resident) ----
    {
        int m4i = t & 15;
        int rg  = t >> 4;
        float4 acc = {0.f, 0.f, 0.f, 0.f};
        const float4* base = (const float4*)(mem + (boff + n0) * MM);
        #pragma unroll 8
        for (int i = 0; i < 32; ++i) {
            int row = rg + i * 16;
            float4 v = base[(size_t)row * 16 + m4i];
            float wv = wp_sh[row];
            acc.x += wv * v.x; acc.y += wv * v.y;
            acc.z += wv * v.z; acc.w += wv * v.w;
        }
        acc_sh[t] = acc;
        __syncthreads();
        if (t < 16) {
            float4 s = {0.f, 0.f, 0.f, 0.f};
            for (int j = 0; j < 16; ++j) {
                float4 v = acc_sh[t + j * 16];
                s.x += v.x; s.y += v.y; s.z += v.z; s.w += v.w;
            }
            ((float4*)(rpart + ((size_t)b * NC + c) * MM))[t] = s;
        }
    }
}

// ---------------- kernel 3: normalize w and r by psum+eps -------------------
__global__ void k_norm(const float* __restrict__ wpb,
                       const float* __restrict__ ppart,
                       const float* __restrict__ rpart,
                       float* __restrict__ r_out,
                       float* __restrict__ w_out) {
    const int c = blockIdx.x;
    const int b = blockIdx.y;
    const int t = threadIdx.x;
    float ps = 0.f;
    #pragma unroll
    for (int i = 0; i < NC; ++i) ps += ppart[b * NC + i];
    const float invz = 1.f / (ps + 1e-16f);
    const size_t boff = (size_t)b * NN + (size_t)c * CHUNK;
    float2 v = ((const float2*)(wpb + boff))[t];
    ((float2*)(w_out + boff))[t] = make_float2(v.x * invz, v.y * invz);
    if (c == 0 && t < MM) {
        float r = 0.f;
        #pragma unroll
        for (int i = 0; i < NC; ++i) r += rpart[((size_t)b * NC + i) * MM + t];
        r_out[(size_t)b * MM + t] = r * invz;
    }
}

// ---------------------------------------------------------------------------
extern "C" void kernel_launch(void* const* d_in, const int* in_sizes, int n_in,
                              void* d_out, int out_size, void* d_ws, size_t ws_size,
                              hipStream_t stream) {
    const float* emb    = (const float*)d_in[0];   // B x CTRL
    const float* w_prev = (const float*)d_in[1];   // B x N
    const float* mem    = (const float*)d_in[2];   // B x N x M
    const float* fc_w   = (const float*)d_in[3];   // OD x CTRL
    const float* fc_b   = (const float*)d_in[4];   // OD

    float* r_out = (float*)d_out;                  // B x M
    float* w_out = r_out + (size_t)B * MM;         // B x N

    // workspace layout (fp32)
    float* evb   = (float*)d_ws;                   // B x N
    float* wpb   = evb + (size_t)B * NN;           // B x N
    float* zpart = wpb + (size_t)B * NN;           // B x NC
    float* ppart = zpart + (size_t)B * NC;         // B x NC
    float* rpart = ppart + (size_t)B * NC;         // B x NC x M

    k_sim <<<dim3(NC, B), 256, 0, stream>>>(emb, fc_w, fc_b, mem, evb, zpart);
    k_wr  <<<dim3(NC, B), 256, 0, stream>>>(emb, fc_w, fc_b, mem, w_prev, evb,
                                            zpart, wpb, ppart, rpart);
    k_norm<<<dim3(NC, B), 256, 0, stream>>>(wpb, ppart, rpart, r_out, w_out);
}